// Round 15
// baseline (45.743 us; speedup 1.0000x reference)
//
#include <hip/hip_runtime.h>

#define B_ 16
#define N_ 128
#define A_ 32
#define O_ 64
#define VD_ 768
#define H_ 1024

typedef short s16x8 __attribute__((ext_vector_type(8)));
typedef short s16x4 __attribute__((ext_vector_type(4)));
typedef float f32x4 __attribute__((ext_vector_type(4)));

#define MFMA(a, b, c) __builtin_amdgcn_mfma_f32_16x16x32_bf16(a, b, c, 0, 0, 0)

__device__ __forceinline__ short bf_hi(float x) {
    return (short)(__float_as_uint(x) >> 16);
}
__device__ __forceinline__ float bf2f(short s) {
    return __uint_as_float(((unsigned)(unsigned short)s) << 16);
}
__device__ __forceinline__ void cvthi8(const float4& f0, const float4& f1,
                                       s16x8& hi) {
    const float ff[8] = {f0.x, f0.y, f0.z, f0.w, f1.x, f1.y, f1.z, f1.w};
    #pragma unroll
    for (int e = 0; e < 8; ++e) hi[e] = bf_hi(ff[e]);
}

__device__ __forceinline__ void gload16(const void* g, void* l) {
    __builtin_amdgcn_global_load_lds(
        (const __attribute__((address_space(1))) void*)g,
        (__attribute__((address_space(3))) void*)l, 16, 0, 0);
}

// ---------------------------------------------------------------------------
// Pre-convert f32 -> bf16-hi for obj, q, vw, qw (all hi-only). (verified r13)
// ---------------------------------------------------------------------------
__global__ __launch_bounds__(256)
void cvt_split(const float* __restrict__ obj, const float* __restrict__ q,
               const float* __restrict__ vw, const float* __restrict__ qw,
               short* __restrict__ objh, short* __restrict__ qh,
               short* __restrict__ vwh, short* __restrict__ qwh)
{
    const int bid = blockIdx.x;
    const float* src; short* hi; int base4;
    if (bid < 192)      { src = obj; hi = objh; base4 = bid * 1024; }
    else if (bid < 576) { src = q;   hi = qh;   base4 = (bid - 192) * 1024; }
    else if (bid < 768) { src = vw;  hi = vwh;  base4 = (bid - 576) * 1024; }
    else                { src = qw;  hi = qwh;  base4 = (bid - 768) * 1024; }
    #pragma unroll
    for (int it = 0; it < 4; ++it) {
        const size_t f4 = (size_t)base4 + it * 256 + threadIdx.x;
        const float4 v = *(const float4*)(src + f4 * 4);
        const float ff[4] = {v.x, v.y, v.z, v.w};
        s16x4 h4;
        #pragma unroll
        for (int e = 0; e < 4; ++e) h4[e] = bf_hi(ff[e]);
        *(s16x4*)(hi + f4 * 4) = h4;
    }
}

// ---------------------------------------------------------------------------
// Unified NT GEMM (bf16-hi x bf16-hi), TRIPLE-buffered counted-vmcnt pipeline
// (byte-identical to the r14 passing version).
// ---------------------------------------------------------------------------
__global__ __launch_bounds__(256, 3)
void gemm_split(const short* __restrict__ objh, const short* __restrict__ qh,
                const short* __restrict__ vwh, const short* __restrict__ qwh,
                const float* __restrict__ qb, const float* __restrict__ lwp,
                short* __restrict__ Wth, short* __restrict__ ubh)
{
    __shared__ __align__(16) short lds3[3][2][4096];   // [buf][X|B][64x64]
    const int bid = blockIdx.x;
    const bool isA = bid < 256;
    const int lb_ = isA ? bid : bid - 256;
    const int r0 = (lb_ >> 4) * 64;
    const int h0 = (lb_ & 15) * 64;
    const short* Xh = isA ? objh : qh;
    const short* Bh = isA ? vwh : qwh;

    const int tid = threadIdx.x;
    const int w = tid >> 6, l = tid & 63;
    const int wm = (w >> 1) * 32, wn = (w & 1) * 32;
    const int g = l >> 4, c16 = l & 15;

    const int row0 = tid >> 3, u0 = (tid & 7) ^ (row0 & 7);
    const int unit1 = 256 + tid;
    const int row1 = unit1 >> 3, u1 = (unit1 & 7) ^ (row1 & 7);
    const short* pXh = Xh + (size_t)r0 * VD_;
    const short* pBh = Bh + (size_t)h0 * VD_;
    const int go0 = row0 * VD_ + u0 * 8;
    const int go1 = row1 * VD_ + u1 * 8;
    const int wo = w * 512;

#define STAGE(BP, CI) do { \
        const int co_ = (CI) * 64; \
        gload16(pXh + go0 + co_, (BP) + wo); \
        gload16(pXh + go1 + co_, (BP) + wo + 2048); \
        gload16(pBh + go0 + co_, (BP) + 4096 + wo); \
        gload16(pBh + go1 + co_, (BP) + 4096 + wo + 2048); \
    } while (0)

    short* b0 = &lds3[0][0][0];    // consumed at iter c
    short* b1 = &lds3[1][0][0];    // iter c+1
    short* b2 = &lds3[2][0][0];    // iter c+2
    STAGE(b0, 0);
    STAGE(b1, 1);
    STAGE(b2, 2);

    f32x4 acc[2][2] = {};

    for (int c = 0; c < VD_ / 64; ++c) {
        if (c < 10)      asm volatile("s_waitcnt vmcnt(8)" ::: "memory");
        else if (c == 10) asm volatile("s_waitcnt vmcnt(4)" ::: "memory");
        else             asm volatile("s_waitcnt vmcnt(0)" ::: "memory");
        asm volatile("s_barrier" ::: "memory");   // all waves' S(c) landed

        const short* bX = b0;
        const short* bB = b0 + 4096;
        #pragma unroll
        for (int s = 0; s < 2; ++s) {
            s16x8 ah[2], bh2[2];
            #pragma unroll
            for (int i = 0; i < 2; ++i) {
                const int m = wm + i * 16 + c16;
                const int us = (((s * 4 + g) ^ (m & 7)) * 8);
                ah[i]  = *(const s16x8*)&bX[m * 64 + us];
                const int n = wn + i * 16 + c16;
                const int vs = (((s * 4 + g) ^ (n & 7)) * 8);
                bh2[i] = *(const s16x8*)&bB[n * 64 + vs];
            }
            #pragma unroll
            for (int i = 0; i < 2; ++i)
                #pragma unroll
                for (int j = 0; j < 2; ++j)
                    acc[i][j] = MFMA(ah[i], bh2[j], acc[i][j]);
        }

        asm volatile("s_waitcnt lgkmcnt(0)" ::: "memory");
        __builtin_amdgcn_sched_barrier(0);
        asm volatile("s_barrier" ::: "memory");   // all waves done reading b0
        if (c + 3 < VD_ / 64) STAGE(b0, c + 3);   // reuse just-consumed buffer
        short* tmp = b0; b0 = b1; b1 = b2; b2 = tmp;
    }
#undef STAGE

    #pragma unroll
    for (int i = 0; i < 2; ++i)
        #pragma unroll
        for (int j = 0; j < 2; ++j) {
            const int h = h0 + wn + j * 16 + c16;
            if (isA) {
                const int o = wm + i * 16 + g * 4;
                s16x4 hi4;
                #pragma unroll
                for (int r = 0; r < 4; ++r) hi4[r] = bf_hi(acc[i][j][r]);
                const size_t dst = ((size_t)(lb_ >> 4) * H_ + h) * O_ + o;
                *(s16x4*)&Wth[dst] = hi4;
            } else {
                const float bv = qb[h], sv = lwp[h];
                #pragma unroll
                for (int r = 0; r < 4; ++r) {
                    const int m = r0 + wm + i * 16 + g * 4 + r;
                    ubh[(size_t)m * H_ + h] =
                        bf_hi(fmaxf(acc[i][j][r] + bv, 0.f) * sv);
                }
            }
        }
}

// ---------------------------------------------------------------------------
// Fused v6: same verified v5 math/structure, but wave-private W staging is
// 2-AHEAD with 3 slabs (pointer rotation). Ledger (2 loads/STAGEW; S(0)
// drained by the prologue __syncthreads, S(1) issued after it): iter t<14
// issues S(t+2) -> outstanding <= 6 -> vmcnt(4) retires S(t); t=14 ->
// vmcnt(2); t=15 -> vmcnt(0). Slab written at t was freed by this wave's
// own reads at t-1 -> still ZERO barriers. LDS 41.8 KB -> 3 blocks/CU.
// ---------------------------------------------------------------------------
__global__ __launch_bounds__(256, 3)
void fused_logits(const float* __restrict__ att1, const short* __restrict__ Wth,
                  const short* __restrict__ ubh, const float* __restrict__ vb,
                  const int* __restrict__ tags, const int* __restrict__ tptr,
                  const float* __restrict__ lbptr, float* __restrict__ out)
{
    __shared__ __align__(16) short Ah[64 * 64];                // 8 KB
    __shared__ __align__(16) short Wc[3][4096];                // 24 KB
    __shared__ short ut[2][1024];                              // 4 KB (bf16)
    __shared__ float vbl[1024];                                // 4 KB
    __shared__ float lgp[4][64];                               // 1 KB

    const int blk = blockIdx.x;          // b*64 + pair
    const int b = blk >> 6;
    const int n0 = (blk & 63) * 2;
    const int tid = threadIdx.x;
    const size_t base_row = (size_t)(b * N_ + n0) * A_;

    const int w = tid >> 6, l = tid & 63;
    const int g = l >> 4, c16 = l & 15;

    const int r0l = l >> 3;                  // 0..7
    const int cu  = (l & 7) ^ r0l;           // source col-unit pre-swizzle
    const short* pW = Wth + (size_t)b * (H_ * O_) + w * 1024 + r0l * 64 + cu * 8;
    const int dwo = w * 1024 + l * 8;        // wave-private slab offset

#define STAGEW(SP, CI) do { \
        const short* ph_ = pW + (size_t)(CI) * 4096; \
        gload16(ph_,       (SP) + dwo); \
        gload16(ph_ + 512, (SP) + dwo + 512); \
    } while (0)

    short* s0 = &Wc[0][0];    // slab read at iter t
    short* s1 = &Wc[1][0];    // t+1
    short* s2 = &Wc[2][0];    // t+2 (staged in-loop)

    STAGEW(s0, 0);

    {   // stage att1 tile as swizzled bf16-hi
        const int row = tid >> 2, qq = tid & 3;
        const float* src = att1 + (base_row + row) * O_ + qq * 16;
        #pragma unroll
        for (int uu = 0; uu < 2; ++uu) {
            const float4 f0 = *(const float4*)(src + uu * 8);
            const float4 f1 = *(const float4*)(src + uu * 8 + 4);
            const int us = ((qq * 2 + uu) ^ (row & 7)) * 8;
            s16x8 hi;
            cvthi8(f0, f1, hi);
            *(s16x8*)&Ah[row * 64 + us] = hi;
        }
    }

    {   // u rows (bf16) and vb (f32) -> LDS tables
        const short* u0g = ubh + (size_t)(b * N_ + n0) * H_;
        const short* u1g = u0g + H_;
        *(s16x4*)&ut[0][tid * 4] = *(const s16x4*)(u0g + tid * 4);
        *(s16x4*)&ut[1][tid * 4] = *(const s16x4*)(u1g + tid * 4);
        *(float4*)&vbl[tid * 4]  = *(const float4*)(vb + tid * 4);
    }

    __syncthreads();     // full drain: vmcnt baseline 0; S(0)/A/u/vb visible

    STAGEW(s1, 1);       // outstanding: 2

    s16x8 ahf[4][2];
    #pragma unroll
    for (int i = 0; i < 4; ++i)
        #pragma unroll
        for (int s = 0; s < 2; ++s) {
            const int m = i * 16 + c16;
            const int us = ((s * 4 + g) ^ (m & 7)) * 8;
            ahf[i][s] = *(const s16x8*)&Ah[m * 64 + us];
        }

    const int sr = c16 & 7;
    const int rbo = w * 1024 + c16 * 64;
    const int ubo0 = (g ^ sr) * 8;
    const int ubo1 = ((g + 4) ^ sr) * 8;
    const int ulane = w * 16 + c16;

    f32x4 part[4] = {};

    // Zero-barrier wave-private pipeline, 2 chunks ahead.
    #pragma unroll 2
    for (int t = 0; t < 16; ++t) {
        if (t < 14) {
            STAGEW(s2, t + 2);
            asm volatile("s_waitcnt vmcnt(4)" ::: "memory");   // retires S(t)
        } else if (t == 14) {
            asm volatile("s_waitcnt vmcnt(2)" ::: "memory");
        } else {
            asm volatile("s_waitcnt vmcnt(0)" ::: "memory");
        }
        const float vbv = vbl[t * 64 + ulane];
        const float uu0 = bf2f(ut[0][t * 64 + ulane]);
        const float uu1 = bf2f(ut[1][t * 64 + ulane]);
        const s16x8 bh0 = *(const s16x8*)&s0[rbo + ubo0];
        const s16x8 bh1 = *(const s16x8*)&s0[rbo + ubo1];
        #pragma unroll
        for (int i = 0; i < 4; ++i) {
            f32x4 acc = {};
            acc = MFMA(ahf[i][0], bh0, acc);
            acc = MFMA(ahf[i][1], bh1, acc);
            const float uu = (i < 2) ? uu0 : uu1;
            #pragma unroll
            for (int r = 0; r < 4; ++r)
                part[i][r] += fmaxf(acc[r] + vbv, 0.f) * uu;
        }
        short* tmp = s0; s0 = s1; s1 = s2; s2 = tmp;   // rotate slabs
    }
#undef STAGEW

    __syncthreads();

    #pragma unroll
    for (int i = 0; i < 4; ++i)
        #pragma unroll
        for (int r = 0; r < 4; ++r) {
            float v = part[i][r];
            v += __shfl_xor(v, 1, 64);
            v += __shfl_xor(v, 2, 64);
            v += __shfl_xor(v, 4, 64);
            v += __shfl_xor(v, 8, 64);
            if (c16 == 0) lgp[w][i * 16 + g * 4 + r] = v;
        }
    __syncthreads();

    float* sml = &vbl[0];
    if (tid < 64) {
        const float tf = (float)(*tptr);
        const float lsum = lgp[0][tid] + lgp[1][tid] + lgp[2][tid] + lgp[3][tid];
        const float lv = (lsum + *lbptr) / tf;
        const int tg = tags[base_row + tid];
        sml[tid] = (tg > 0) ? lv : -1e30f;
    }
    __syncthreads();

    if (tid < 128) {
        const int nn = tid >> 6, o = tid & 63;
        const float* lr = &sml[nn * 32];
        float m = -3.0e38f;
        #pragma unroll
        for (int a = 0; a < 32; ++a) m = fmaxf(m, lr[a]);
        float s = 0.f, accum = 0.f;
        #pragma unroll
        for (int a = 0; a < 32; ++a) {
            const float e = __expf(lr[a] - m);
            s += e;
            accum += e * att1[(base_row + nn * 32 + a) * O_ + o];
        }
        out[(size_t)(b * N_ + n0 + nn) * O_ + o] = accum / s;
    }
}

extern "C" void kernel_launch(void* const* d_in, const int* in_sizes, int n_in,
                              void* d_out, int out_size, void* d_ws, size_t ws_size,
                              hipStream_t stream)
{
    const float* q    = (const float*)d_in[0];
    const float* att1 = (const float*)d_in[1];
    const float* obj  = (const float*)d_in[2];
    const int*   tags = (const int*)d_in[3];
    const int*   tptr = (const int*)d_in[4];
    const float* vw   = (const float*)d_in[5];
    const float* vb   = (const float*)d_in[6];
    const float* qw   = (const float*)d_in[7];
    const float* qb   = (const float*)d_in[8];
    const float* lw   = (const float*)d_in[9];
    const float* lb   = (const float*)d_in[10];
    float* out = (float*)d_out;

    short* ubh  = (short*)d_ws;                         // [2048][1024] bf16  4 MB
    short* Wth  = ubh + (size_t)B_ * N_ * H_;           // [16][1024][64]     2 MB
    short* objh = Wth + (size_t)B_ * H_ * O_;           // [1024][768] hi     1.5 MB
    short* qh   = objh + (size_t)1024 * VD_;            // [2048][768] hi     3 MB
    short* vwh  = qh + (size_t)2048 * VD_;              // [1024][768] hi     1.5 MB
    short* qwh  = vwh + (size_t)H_ * VD_;               // [1024][768] hi     1.5 MB

    cvt_split<<<960, 256, 0, stream>>>(obj, q, vw, qw, objh, qh, vwh, qwh);
    gemm_split<<<768, 256, 0, stream>>>(objh, qh, vwh, qwh, qb, lw, Wth, ubh);
    fused_logits<<<B_ * 64, 256, 0, stream>>>(att1, Wth, ubh, vb, tags,
                                              tptr, lb, out);
}

// Round 16
// 40.784 us; speedup vs baseline: 1.1216x; 1.1216x over previous
//
#include <hip/hip_runtime.h>

#define B_ 16
#define N_ 128
#define A_ 32
#define O_ 64
#define VD_ 768
#define H_ 1024

typedef short s16x8 __attribute__((ext_vector_type(8)));
typedef short s16x4 __attribute__((ext_vector_type(4)));
typedef float f32x4 __attribute__((ext_vector_type(4)));

#define MFMA(a, b, c) __builtin_amdgcn_mfma_f32_16x16x32_bf16(a, b, c, 0, 0, 0)

__device__ __forceinline__ short bf_hi(float x) {
    return (short)(__float_as_uint(x) >> 16);
}
__device__ __forceinline__ float bf2f(short s) {
    return __uint_as_float(((unsigned)(unsigned short)s) << 16);
}
__device__ __forceinline__ void cvthi8(const float4& f0, const float4& f1,
                                       s16x8& hi) {
    const float ff[8] = {f0.x, f0.y, f0.z, f0.w, f1.x, f1.y, f1.z, f1.w};
    #pragma unroll
    for (int e = 0; e < 8; ++e) hi[e] = bf_hi(ff[e]);
}

__device__ __forceinline__ void gload16(const void* g, void* l) {
    __builtin_amdgcn_global_load_lds(
        (const __attribute__((address_space(1))) void*)g,
        (__attribute__((address_space(3))) void*)l, 16, 0, 0);
}

// ---------------------------------------------------------------------------
// Pre-convert f32 -> bf16-hi for obj, q, vw, qw (all hi-only). (verified r13)
// ---------------------------------------------------------------------------
__global__ __launch_bounds__(256)
void cvt_split(const float* __restrict__ obj, const float* __restrict__ q,
               const float* __restrict__ vw, const float* __restrict__ qw,
               short* __restrict__ objh, short* __restrict__ qh,
               short* __restrict__ vwh, short* __restrict__ qwh)
{
    const int bid = blockIdx.x;
    const float* src; short* hi; int base4;
    if (bid < 192)      { src = obj; hi = objh; base4 = bid * 1024; }
    else if (bid < 576) { src = q;   hi = qh;   base4 = (bid - 192) * 1024; }
    else if (bid < 768) { src = vw;  hi = vwh;  base4 = (bid - 576) * 1024; }
    else                { src = qw;  hi = qwh;  base4 = (bid - 768) * 1024; }
    #pragma unroll
    for (int it = 0; it < 4; ++it) {
        const size_t f4 = (size_t)base4 + it * 256 + threadIdx.x;
        const float4 v = *(const float4*)(src + f4 * 4);
        const float ff[4] = {v.x, v.y, v.z, v.w};
        s16x4 h4;
        #pragma unroll
        for (int e = 0; e < 4; ++e) h4[e] = bf_hi(ff[e]);
        *(s16x4*)(hi + f4 * 4) = h4;
    }
}

// ---------------------------------------------------------------------------
// Unified NT GEMM (bf16-hi x bf16-hi), TRIPLE-buffered counted-vmcnt pipeline
// (byte-identical to the r14 passing version).
// ---------------------------------------------------------------------------
__global__ __launch_bounds__(256, 3)
void gemm_split(const short* __restrict__ objh, const short* __restrict__ qh,
                const short* __restrict__ vwh, const short* __restrict__ qwh,
                const float* __restrict__ qb, const float* __restrict__ lwp,
                short* __restrict__ Wth, short* __restrict__ ubh)
{
    __shared__ __align__(16) short lds3[3][2][4096];   // [buf][X|B][64x64]
    const int bid = blockIdx.x;
    const bool isA = bid < 256;
    const int lb_ = isA ? bid : bid - 256;
    const int r0 = (lb_ >> 4) * 64;
    const int h0 = (lb_ & 15) * 64;
    const short* Xh = isA ? objh : qh;
    const short* Bh = isA ? vwh : qwh;

    const int tid = threadIdx.x;
    const int w = tid >> 6, l = tid & 63;
    const int wm = (w >> 1) * 32, wn = (w & 1) * 32;
    const int g = l >> 4, c16 = l & 15;

    const int row0 = tid >> 3, u0 = (tid & 7) ^ (row0 & 7);
    const int unit1 = 256 + tid;
    const int row1 = unit1 >> 3, u1 = (unit1 & 7) ^ (row1 & 7);
    const short* pXh = Xh + (size_t)r0 * VD_;
    const short* pBh = Bh + (size_t)h0 * VD_;
    const int go0 = row0 * VD_ + u0 * 8;
    const int go1 = row1 * VD_ + u1 * 8;
    const int wo = w * 512;

#define STAGE(BP, CI) do { \
        const int co_ = (CI) * 64; \
        gload16(pXh + go0 + co_, (BP) + wo); \
        gload16(pXh + go1 + co_, (BP) + wo + 2048); \
        gload16(pBh + go0 + co_, (BP) + 4096 + wo); \
        gload16(pBh + go1 + co_, (BP) + 4096 + wo + 2048); \
    } while (0)

    short* b0 = &lds3[0][0][0];    // consumed at iter c
    short* b1 = &lds3[1][0][0];    // iter c+1
    short* b2 = &lds3[2][0][0];    // iter c+2
    STAGE(b0, 0);
    STAGE(b1, 1);
    STAGE(b2, 2);

    f32x4 acc[2][2] = {};

    for (int c = 0; c < VD_ / 64; ++c) {
        if (c < 10)      asm volatile("s_waitcnt vmcnt(8)" ::: "memory");
        else if (c == 10) asm volatile("s_waitcnt vmcnt(4)" ::: "memory");
        else             asm volatile("s_waitcnt vmcnt(0)" ::: "memory");
        asm volatile("s_barrier" ::: "memory");   // all waves' S(c) landed

        const short* bX = b0;
        const short* bB = b0 + 4096;
        #pragma unroll
        for (int s = 0; s < 2; ++s) {
            s16x8 ah[2], bh2[2];
            #pragma unroll
            for (int i = 0; i < 2; ++i) {
                const int m = wm + i * 16 + c16;
                const int us = (((s * 4 + g) ^ (m & 7)) * 8);
                ah[i]  = *(const s16x8*)&bX[m * 64 + us];
                const int n = wn + i * 16 + c16;
                const int vs = (((s * 4 + g) ^ (n & 7)) * 8);
                bh2[i] = *(const s16x8*)&bB[n * 64 + vs];
            }
            #pragma unroll
            for (int i = 0; i < 2; ++i)
                #pragma unroll
                for (int j = 0; j < 2; ++j)
                    acc[i][j] = MFMA(ah[i], bh2[j], acc[i][j]);
        }

        asm volatile("s_waitcnt lgkmcnt(0)" ::: "memory");
        __builtin_amdgcn_sched_barrier(0);
        asm volatile("s_barrier" ::: "memory");   // all waves done reading b0
        if (c + 3 < VD_ / 64) STAGE(b0, c + 3);   // reuse just-consumed buffer
        short* tmp = b0; b0 = b1; b1 = b2; b2 = tmp;
    }
#undef STAGE

    #pragma unroll
    for (int i = 0; i < 2; ++i)
        #pragma unroll
        for (int j = 0; j < 2; ++j) {
            const int h = h0 + wn + j * 16 + c16;
            if (isA) {
                const int o = wm + i * 16 + g * 4;
                s16x4 hi4;
                #pragma unroll
                for (int r = 0; r < 4; ++r) hi4[r] = bf_hi(acc[i][j][r]);
                const size_t dst = ((size_t)(lb_ >> 4) * H_ + h) * O_ + o;
                *(s16x4*)&Wth[dst] = hi4;
            } else {
                const float bv = qb[h], sv = lwp[h];
                #pragma unroll
                for (int r = 0; r < 4; ++r) {
                    const int m = r0 + wm + i * 16 + g * 4 + r;
                    ubh[(size_t)m * H_ + h] =
                        bf_hi(fmaxf(acc[i][j][r] + bv, 0.f) * sv);
                }
            }
        }
}

// ---------------------------------------------------------------------------
// Fused v5 (byte-identical structure to the r14 passing version; 2-slab,
// 1-ahead wave-private staging, zero barriers, vmcnt(2); LDS 33.8 KB ->
// 4 blocks/CU). Added: bijective XCD swizzle of the block index so all 64
// blocks sharing W[b] / ub[b] land on the same XCD's L2.
// ---------------------------------------------------------------------------
__global__ __launch_bounds__(256, 4)
void fused_logits(const float* __restrict__ att1, const short* __restrict__ Wth,
                  const short* __restrict__ ubh, const float* __restrict__ vb,
                  const int* __restrict__ tags, const int* __restrict__ tptr,
                  const float* __restrict__ lbptr, float* __restrict__ out)
{
    __shared__ __align__(16) short Ah[64 * 64];                // 8 KB
    __shared__ __align__(16) short Wc[2][4096];                // 16 KB
    __shared__ short ut[2][1024];                              // 4 KB (bf16)
    __shared__ float vbl[1024];                                // 4 KB
    __shared__ float lgp[4][64];                               // 1 KB

    // XCD-aware bijective swizzle: 1024 blocks = 8 XCDs x 128. Same-b groups
    // (64 consecutive logical blocks) map to one XCD -> W[b]/ub L2 locality.
    const int blk = (blockIdx.x & 7) * 128 + (blockIdx.x >> 3);
    const int b = blk >> 6;
    const int n0 = (blk & 63) * 2;
    const int tid = threadIdx.x;
    const size_t base_row = (size_t)(b * N_ + n0) * A_;

    const int w = tid >> 6, l = tid & 63;
    const int g = l >> 4, c16 = l & 15;

    const int r0l = l >> 3;                  // 0..7
    const int cu  = (l & 7) ^ r0l;           // source col-unit pre-swizzle
    const short* pW = Wth + (size_t)b * (H_ * O_) + w * 1024 + r0l * 64 + cu * 8;
    short* const dW = &Wc[0][w * 1024 + l * 8];

#define STAGEW(BUFOFF, CI) do { \
        const short* ph_ = pW + (size_t)(CI) * 4096; \
        gload16(ph_,       dW + (BUFOFF)); \
        gload16(ph_ + 512, dW + (BUFOFF) + 512); \
    } while (0)

    STAGEW(0, 0);

    {   // stage att1 tile as swizzled bf16-hi
        const int row = tid >> 2, qq = tid & 3;
        const float* src = att1 + (base_row + row) * O_ + qq * 16;
        #pragma unroll
        for (int uu = 0; uu < 2; ++uu) {
            const float4 f0 = *(const float4*)(src + uu * 8);
            const float4 f1 = *(const float4*)(src + uu * 8 + 4);
            const int us = ((qq * 2 + uu) ^ (row & 7)) * 8;
            s16x8 hi;
            cvthi8(f0, f1, hi);
            *(s16x8*)&Ah[row * 64 + us] = hi;
        }
    }

    {   // u rows (bf16) and vb (f32) -> LDS tables
        const short* u0g = ubh + (size_t)(b * N_ + n0) * H_;
        const short* u1g = u0g + H_;
        *(s16x4*)&ut[0][tid * 4] = *(const s16x4*)(u0g + tid * 4);
        *(s16x4*)&ut[1][tid * 4] = *(const s16x4*)(u1g + tid * 4);
        *(float4*)&vbl[tid * 4]  = *(const float4*)(vb + tid * 4);
    }

    __syncthreads();     // full drain: vmcnt baseline 0

    s16x8 ahf[4][2];
    #pragma unroll
    for (int i = 0; i < 4; ++i)
        #pragma unroll
        for (int s = 0; s < 2; ++s) {
            const int m = i * 16 + c16;
            const int us = ((s * 4 + g) ^ (m & 7)) * 8;
            ahf[i][s] = *(const s16x8*)&Ah[m * 64 + us];
        }

    const int sr = c16 & 7;
    const int rb = w * 1024 + c16 * 64;
    const int ubo0 = (g ^ sr) * 8;
    const int ubo1 = ((g + 4) ^ sr) * 8;
    const int ulane = w * 16 + c16;

    f32x4 part[4] = {};

    #pragma unroll 2
    for (int t = 0; t < 16; ++t) {
        if (t < 15) {
            STAGEW(((t + 1) & 1) * 4096, t + 1);
            asm volatile("s_waitcnt vmcnt(2)" ::: "memory");
        } else {
            asm volatile("s_waitcnt vmcnt(0)" ::: "memory");
        }
        const int bufo = (t & 1) * 4096;
        const float vbv = vbl[t * 64 + ulane];
        const float uu0 = bf2f(ut[0][t * 64 + ulane]);
        const float uu1 = bf2f(ut[1][t * 64 + ulane]);
        const s16x8 bh0 = *(const s16x8*)&Wc[0][bufo + rb + ubo0];
        const s16x8 bh1 = *(const s16x8*)&Wc[0][bufo + rb + ubo1];
        #pragma unroll
        for (int i = 0; i < 4; ++i) {
            f32x4 acc = {};
            acc = MFMA(ahf[i][0], bh0, acc);
            acc = MFMA(ahf[i][1], bh1, acc);
            const float uu = (i < 2) ? uu0 : uu1;
            #pragma unroll
            for (int r = 0; r < 4; ++r)
                part[i][r] += fmaxf(acc[r] + vbv, 0.f) * uu;
        }
    }
#undef STAGEW

    __syncthreads();

    #pragma unroll
    for (int i = 0; i < 4; ++i)
        #pragma unroll
        for (int r = 0; r < 4; ++r) {
            float v = part[i][r];
            v += __shfl_xor(v, 1, 64);
            v += __shfl_xor(v, 2, 64);
            v += __shfl_xor(v, 4, 64);
            v += __shfl_xor(v, 8, 64);
            if (c16 == 0) lgp[w][i * 16 + g * 4 + r] = v;
        }
    __syncthreads();

    float* sml = &vbl[0];
    if (tid < 64) {
        const float tf = (float)(*tptr);
        const float lsum = lgp[0][tid] + lgp[1][tid] + lgp[2][tid] + lgp[3][tid];
        const float lv = (lsum + *lbptr) / tf;
        const int tg = tags[base_row + tid];
        sml[tid] = (tg > 0) ? lv : -1e30f;
    }
    __syncthreads();

    if (tid < 128) {
        const int nn = tid >> 6, o = tid & 63;
        const float* lr = &sml[nn * 32];
        float m = -3.0e38f;
        #pragma unroll
        for (int a = 0; a < 32; ++a) m = fmaxf(m, lr[a]);
        float s = 0.f, accum = 0.f;
        #pragma unroll
        for (int a = 0; a < 32; ++a) {
            const float e = __expf(lr[a] - m);
            s += e;
            accum += e * att1[(base_row + nn * 32 + a) * O_ + o];
        }
        out[(size_t)(b * N_ + n0 + nn) * O_ + o] = accum / s;
    }
}

extern "C" void kernel_launch(void* const* d_in, const int* in_sizes, int n_in,
                              void* d_out, int out_size, void* d_ws, size_t ws_size,
                              hipStream_t stream)
{
    const float* q    = (const float*)d_in[0];
    const float* att1 = (const float*)d_in[1];
    const float* obj  = (const float*)d_in[2];
    const int*   tags = (const int*)d_in[3];
    const int*   tptr = (const int*)d_in[4];
    const float* vw   = (const float*)d_in[5];
    const float* vb   = (const float*)d_in[6];
    const float* qw   = (const float*)d_in[7];
    const float* qb   = (const float*)d_in[8];
    const float* lw   = (const float*)d_in[9];
    const float* lb   = (const float*)d_in[10];
    float* out = (float*)d_out;

    short* ubh  = (short*)d_ws;                         // [2048][1024] bf16  4 MB
    short* Wth  = ubh + (size_t)B_ * N_ * H_;           // [16][1024][64]     2 MB
    short* objh = Wth + (size_t)B_ * H_ * O_;           // [1024][768] hi     1.5 MB
    short* qh   = objh + (size_t)1024 * VD_;            // [2048][768] hi     3 MB
    short* vwh  = qh + (size_t)2048 * VD_;              // [1024][768] hi     1.5 MB
    short* qwh  = vwh + (size_t)H_ * VD_;               // [1024][768] hi     1.5 MB

    cvt_split<<<960, 256, 0, stream>>>(obj, q, vw, qw, objh, qh, vwh, qwh);
    gemm_split<<<768, 256, 0, stream>>>(objh, qh, vwh, qwh, qb, lw, Wth, ubh);
    fused_logits<<<B_ * 64, 256, 0, stream>>>(att1, Wth, ubh, vb, tags,
                                              tptr, lb, out);
}